// Round 1
// baseline (145.975 us; speedup 1.0000x reference)
//
#include <hip/hip_runtime.h>

// Problem constants (B=2048, F=512, U=512, G=64, REG_STRENGTH=1.0)
#define B_SZ 2048
#define F_SZ 512
#define U_SZ 512
#define G_SZ 64
#define REG_STRENGTH 1.0f

// One fused kernel: block = (group g, 64-col n-tile). 256 threads = 4 waves,
// each wave owns 16 output cols. W (B-operand) lives in registers; X (A) is
// staged in LDS (double-buffered, XOR-swizzled), split fp32 -> bf16 hi/lo,
// 3x mfma_f32_16x16x32_bf16 per tile (fp32-grade accuracy).
#define NT 8                 // n-tiles per group (64 cols each)
#define BN 64
#define BK 64                // fp32 k elements staged per step
#define NSTEP (F_SZ / BK)    // 8
#define MROWS 64             // rows per chunk (cnt ~ Binomial(2048,1/64) ~ 32)
#define THREADS 256
#define NBLOCKS (NT * G_SZ)  // 512

typedef float f32x4 __attribute__((ext_vector_type(4)));
typedef __bf16 bf16x8 __attribute__((ext_vector_type(8)));

#define MFMA(a, b, c) __builtin_amdgcn_mfma_f32_16x16x32_bf16((a), (b), (c), 0, 0, 0)

static __device__ __forceinline__ unsigned short bf16_rne(float f) {
  unsigned u = __float_as_uint(f);
  return (unsigned short)((u + 0x7fffu + ((u >> 16) & 1u)) >> 16);
}

// fp32 -> (hi, lo) bf16 split of 8 values (two float4s). x = hi + lo exactly
// to within 2^-17 rel; dropped lo*lo term in the matmul is O(2^-18).
static __device__ __forceinline__ void cvt8(const f32x4 a, const f32x4 b,
                                            bf16x8& h, bf16x8& l) {
#pragma unroll
  for (int i = 0; i < 4; ++i) {
    const unsigned short hb = bf16_rne(a[i]);
    h[i] = __builtin_bit_cast(__bf16, hb);
    l[i] = __builtin_bit_cast(
        __bf16, bf16_rne(a[i] - __uint_as_float((unsigned)hb << 16)));
  }
#pragma unroll
  for (int i = 0; i < 4; ++i) {
    const unsigned short hb = bf16_rne(b[i]);
    h[4 + i] = __builtin_bit_cast(__bf16, hb);
    l[4 + i] = __builtin_bit_cast(
        __bf16, bf16_rne(b[i] - __uint_as_float((unsigned)hb << 16)));
  }
}

// LDS X tile: row stride 128 B (64 bf16). XOR swizzle byte ^= (row&7)<<4
// spreads the 16-row fragment column read across all banks (2-way max = free).
static __device__ __forceinline__ void writeX(unsigned short* __restrict__ xh,
                                              unsigned short* __restrict__ xl,
                                              int row, int kq, const f32x4 v) {
  int byte = (row << 7) + (kq << 3);
  byte ^= (row & 7) << 4;
  const unsigned short h0 = bf16_rne(v[0]);
  const unsigned short h1 = bf16_rne(v[1]);
  const unsigned short h2 = bf16_rne(v[2]);
  const unsigned short h3 = bf16_rne(v[3]);
  const ushort4 hv = make_ushort4(h0, h1, h2, h3);
  const ushort4 lv = make_ushort4(
      bf16_rne(v[0] - __uint_as_float((unsigned)h0 << 16)),
      bf16_rne(v[1] - __uint_as_float((unsigned)h1 << 16)),
      bf16_rne(v[2] - __uint_as_float((unsigned)h2 << 16)),
      bf16_rne(v[3] - __uint_as_float((unsigned)h3 << 16)));
  *(ushort4*)((char*)xh + byte) = hv;
  *(ushort4*)((char*)xl + byte) = lv;
}

// A-fragment for mfma_f32_16x16x32_bf16: lane holds A[l&15][8*(l>>4)+e].
static __device__ __forceinline__ bf16x8 readA(
    const unsigned short* __restrict__ base, int m, int kk, int llo, int lhi) {
  const int row = (m << 4) + llo;
  int byte = (row << 7) + (kk << 6) + (lhi << 4);
  byte ^= (row & 7) << 4;
  return *(const bf16x8*)((const char*)base + byte);
}

__global__ __launch_bounds__(THREADS, 2) void fused_kernel(
    const float* __restrict__ x, const int* __restrict__ gid,
    const float* __restrict__ w_mu, const float* __restrict__ b_mu,
    const float* __restrict__ w0_mu, const float* __restrict__ b0_mu,
    float* __restrict__ out, float* __restrict__ wsf,
    unsigned* __restrict__ done) {
  __shared__ __align__(16) unsigned short XH[2][MROWS * BK];  // 16 KB
  __shared__ __align__(16) unsigned short XL[2][MROWS * BK];  // 16 KB
  __shared__ int rows_s[B_SZ];                                // 8 KB
  __shared__ int cnt_s;
  __shared__ float red_s[THREADS / 64];

  // XCD co-location: the 8 n-tile blocks of a group land on one XCD
  // (XCD = linear wg id % 8), sharing gid + x rows in that XCD's L2.
  const int f = blockIdx.x;
  const int r8 = f & 7;
  const int q = f >> 3;          // 0..63
  const int nt = q & 7;          // n-tile 0..7
  const int g = ((q >> 3) << 3) + r8;  // bijective

  const int tid = threadIdx.x;
  const int lane = tid & 63;
  const int wv = tid >> 6;   // wave 0..3 -> 16-col slice
  const int lhi = lane >> 4; // k-chunk within fragment
  const int llo = lane & 15; // row (A) / col (B) within 16-tile

  // ---- per-block gid scan -> row list for this group (order irrelevant) ----
  if (tid == 0) cnt_s = 0;
  __syncthreads();
#pragma unroll
  for (int u = 0; u < 2; ++u) {
    const int4 v = ((const int4*)gid)[tid + u * THREADS];
    const int b0 = (tid + u * THREADS) << 2;
    if (v.x == g) rows_s[atomicAdd(&cnt_s, 1)] = b0;
    if (v.y == g) rows_s[atomicAdd(&cnt_s, 1)] = b0 + 1;
    if (v.z == g) rows_s[atomicAdd(&cnt_s, 1)] = b0 + 2;
    if (v.w == g) rows_s[atomicAdd(&cnt_s, 1)] = b0 + 3;
  }
  __syncthreads();
  const int cnt = cnt_s;

  if (cnt > 0) {
    const int mycol = nt * BN + wv * 16 + llo;  // this lane's output column
    const float* __restrict__ wrow =
        w_mu + (size_t)g * (U_SZ * F_SZ) + (size_t)mycol * F_SZ;
    const float* __restrict__ w0row = w0_mu + (size_t)mycol * F_SZ;

    float regp = 0.0f;
    if (nt == 0) {  // fused bias reg-loss, once per group
      for (int u = tid; u < U_SZ; u += THREADS) {
        const float d = b_mu[(g << 9) + u] - b0_mu[u];
        regp += d * d;
      }
    }

    for (int r0c = 0; r0c < cnt; r0c += MROWS) {  // executes once unless cnt>64
      const int rc = min(MROWS, cnt - r0c);
      const int nf4 = rc << 4;          // float4s per k-step to stage
      const int mt = (rc + 15) >> 4;    // 16-row m-tiles
      const bool doreg = (r0c == 0);
      f32x4 acc[4];
#pragma unroll
      for (int m = 0; m < 4; ++m) acc[m] = (f32x4){0.f, 0.f, 0.f, 0.f};

      // prologue: stage k-step 0 into buffer 0
#pragma unroll
      for (int u = 0; u < 4; ++u) {
        const int i = tid + u * THREADS;
        if (i < nf4) {
          const int row = i >> 4, kq = i & 15;
          const f32x4 v = *(const f32x4*)(
              x + (size_t)rows_s[r0c + row] * F_SZ + (kq << 2));
          writeX(&XH[0][0], &XL[0][0], row, kq, v);
        }
      }
      __syncthreads();

      for (int s = 0; s < NSTEP; ++s) {
        const int buf = s & 1;
        // (1) issue next k-step's X loads early (latency hides under W+MFMA)
        f32x4 xr[4];
        if (s + 1 < NSTEP) {
          const int kc = (s + 1) * BK;
#pragma unroll
          for (int u = 0; u < 4; ++u) {
            const int i = tid + u * THREADS;
            if (i < nf4) {
              const int row = i >> 4, kq = i & 15;
              xr[u] = *(const f32x4*)(
                  x + (size_t)rows_s[r0c + row] * F_SZ + kc + (kq << 2));
            }
          }
        }
        // (2) W for this step: lane loads its own B-fragment slices (8 fp32
        //     per 32-k chunk at k = 8*lhi), no LDS round-trip.
        const int kcs = s * BK + (lhi << 3);
        const f32x4 wa0 = *(const f32x4*)(wrow + kcs);
        const f32x4 wa1 = *(const f32x4*)(wrow + kcs + 4);
        const f32x4 wb0 = *(const f32x4*)(wrow + kcs + 32);
        const f32x4 wb1 = *(const f32x4*)(wrow + kcs + 32 + 4);
        if (doreg) {  // fused W reg-loss: each W element visited exactly once
          const f32x4 z0 = *(const f32x4*)(w0row + kcs);
          const f32x4 z1 = *(const f32x4*)(w0row + kcs + 4);
          const f32x4 z2 = *(const f32x4*)(w0row + kcs + 32);
          const f32x4 z3 = *(const f32x4*)(w0row + kcs + 32 + 4);
#pragma unroll
          for (int i = 0; i < 4; ++i) {
            const float d0 = wa0[i] - z0[i], d1 = wa1[i] - z1[i];
            const float d2 = wb0[i] - z2[i], d3 = wb1[i] - z3[i];
            regp += d0 * d0 + d1 * d1 + d2 * d2 + d3 * d3;
          }
        }
        bf16x8 wh0, wl0, wh1, wl1;
        cvt8(wa0, wa1, wh0, wl0);  // kk = 0
        cvt8(wb0, wb1, wh1, wl1);  // kk = 1
        // (3) MFMA: acc += Ah*Wh + Ah*Wl + Al*Wh  (fp32 accumulate)
#pragma unroll
        for (int m = 0; m < 4; ++m) {
          if (m < mt) {
            const bf16x8 ah0 = readA(&XH[buf][0], m, 0, llo, lhi);
            const bf16x8 al0 = readA(&XL[buf][0], m, 0, llo, lhi);
            acc[m] = MFMA(ah0, wh0, acc[m]);
            acc[m] = MFMA(ah0, wl0, acc[m]);
            acc[m] = MFMA(al0, wh0, acc[m]);
            const bf16x8 ah1 = readA(&XH[buf][0], m, 1, llo, lhi);
            const bf16x8 al1 = readA(&XL[buf][0], m, 1, llo, lhi);
            acc[m] = MFMA(ah1, wh1, acc[m]);
            acc[m] = MFMA(ah1, wl1, acc[m]);
            acc[m] = MFMA(al1, wh1, acc[m]);
          }
        }
        // (4) write prefetched X into the other buffer (write-late, T14)
        if (s + 1 < NSTEP) {
#pragma unroll
          for (int u = 0; u < 4; ++u) {
            const int i = tid + u * THREADS;
            if (i < nf4) {
              const int row = i >> 4, kq = i & 15;
              writeX(&XH[buf ^ 1][0], &XL[buf ^ 1][0], row, kq, xr[u]);
            }
          }
        }
        __syncthreads();
      }

      // epilogue: D row = 4*(lane>>4)+reg, col = lane&15 (verified mapping)
      const float bias = b_mu[(g << 9) + mycol];
#pragma unroll
      for (int m = 0; m < 4; ++m) {
        if (m < mt) {
#pragma unroll
          for (int j = 0; j < 4; ++j) {
            const int rl = (m << 4) + (lhi << 2) + j;
            if (rl < rc) {
              out[(size_t)rows_s[r0c + rl] * U_SZ + mycol] = acc[m][j] + bias;
            }
          }
        }
      }
    }

    // block-reduce reg partials, weight by cnt, one atomic
#pragma unroll
    for (int o = 32; o > 0; o >>= 1) regp += __shfl_down(regp, o, 64);
    if (lane == 0) red_s[wv] = regp;
    __syncthreads();
    if (tid == 0) {
      atomicAdd(wsf, (float)cnt * (red_s[0] + red_s[1] + red_s[2] + red_s[3]));
    }
  }

  // fused finalize: last block to finish writes the reg-loss scalar
  if (tid == 0) {
    __threadfence();
    const unsigned prev = atomicAdd(done, 1u);
    if (prev == (unsigned)(gridDim.x - 1)) {
      __threadfence();
      const float v = atomicAdd(wsf, 0.0f);  // coherent device-scope read
      out[(size_t)B_SZ * U_SZ] = REG_STRENGTH * v;
    }
  }
}

extern "C" void kernel_launch(void* const* d_in, const int* in_sizes, int n_in,
                              void* d_out, int out_size, void* d_ws,
                              size_t ws_size, hipStream_t stream) {
  (void)in_sizes; (void)n_in; (void)out_size; (void)ws_size;
  const float* x     = (const float*)d_in[0];
  const int*   gid   = (const int*)d_in[1];
  const float* w_mu  = (const float*)d_in[2];
  const float* b_mu  = (const float*)d_in[3];
  const float* w0_mu = (const float*)d_in[4];
  const float* b0_mu = (const float*)d_in[5];

  float* wsf = (float*)d_ws;
  unsigned* done = (unsigned*)d_ws + 1;

  hipMemsetAsync(d_ws, 0, 8, stream);
  fused_kernel<<<NBLOCKS, THREADS, 0, stream>>>(x, gid, w_mu, b_mu, w0_mu,
                                                b0_mu, (float*)d_out, wsf, done);
}